// Round 3
// baseline (15674.466 us; speedup 1.0000x reference)
//
#include <hip/hip_runtime.h>
#include <stdint.h>

#define STEPS 100

// ---------------------------------------------------------------------------
// Threefry2x32 (JAX-exact, 20 rounds)
// ---------------------------------------------------------------------------
__device__ __forceinline__ uint32_t rotl32(uint32_t v, int r) {
  return (v << r) | (v >> (32 - r));
}

__device__ __forceinline__ void tf2x32(uint32_t k0, uint32_t k1,
                                       uint32_t x0, uint32_t x1,
                                       uint32_t& o0, uint32_t& o1) {
  uint32_t ks2 = k0 ^ k1 ^ 0x1BD11BDAu;
  x0 += k0; x1 += k1;
#define RND(r) { x0 += x1; x1 = rotl32(x1, (r)); x1 ^= x0; }
  RND(13) RND(15) RND(26) RND(6)
  x0 += k1;  x1 += ks2 + 1u;
  RND(17) RND(29) RND(16) RND(24)
  x0 += ks2; x1 += k0 + 2u;
  RND(13) RND(15) RND(26) RND(6)
  x0 += k0;  x1 += k1 + 3u;
  RND(17) RND(29) RND(16) RND(24)
  x0 += k1;  x1 += ks2 + 4u;
  RND(13) RND(15) RND(26) RND(6)
  x0 += ks2; x1 += k0 + 5u;
#undef RND
  o0 = x0; o1 = x1;
}

__global__ void keys_k(uint32_t* __restrict__ kb) {
  int i = threadIdx.x;
  if (i < STEPS) {
    uint32_t a, b;
    tf2x32(0u, 42u, 0u, (uint32_t)i, a, b);
    kb[2 * i] = a;
    kb[2 * i + 1] = b;
  }
}

__global__ void wt_k(const float* __restrict__ w2, float* __restrict__ wT) {
  int i = blockIdx.x * blockDim.x + threadIdx.x;
  if (i >= 25000) return;
  int oc = i / 500, q = i % 500;
  wT[q * 50 + oc] = w2[i];
}

// wf0 transpose, padded: wf0T[k*256 + n] = (n<200) ? wf0[n*2450+k] : 0
__global__ void wf0t_k(const float* __restrict__ wf0,
                       float* __restrict__ wf0T) {
  int i = blockIdx.x * blockDim.x + threadIdx.x;
  if (i >= 2450 * 256) return;
  int k = i >> 8, n = i & 255;
  wf0T[i] = (n < 200) ? wf0[n * 2450 + k] : 0.f;
}

// ---------------------------------------------------------------------------
// PERSISTENT per-sample kernel v11: embrace 1 block/CU (the SPI refuses a
// 2nd 512-thr WG above ~64 VGPR: v9 yes@64, v10 no@120), and instead drain
// the saturated CU-global LDS-issue pipe:
//  * sp1 padded [20][18 rows][16 cols] w/ zero halo -> P2 u-row = 4 aligned
//    ds_read_b128, NO guards; one row load feeds both output rows
//    (r0 ky=jr / r1 ky=jr-1): 480 b128/thread/step replaces 3600 guarded
//    b32 + ~4000 guard VALU ops.
//  * pois padded [32][32] -> P1 6x6 patch = 18 float2 loads, guards gone.
//  * wv[25] hoisted out of the row loop (wT global loads halve; VMEM idle).
//  * launch_bounds(512,1): VGPR budget 256, 2 waves/SIMD placement safe.
// Per-output summation order (ic asc, ky asc, kx asc; pads = exact +0,
// same semantics as v10's zero-filled u[]) -> bit-identical output.
// ---------------------------------------------------------------------------
__global__ __launch_bounds__(512, 1) void step_all_k(
    const float* __restrict__ x, const float* __restrict__ w1,
    const float* __restrict__ wT, const uint32_t* __restrict__ kb,
    uint32_t* __restrict__ sp2g) {
  __shared__ float  xhs_l[784];          // x/2 (signed; |.| = |x|/2)
  __shared__ float  pois_l[32 * 32];     // poisson spikes, padded, zero halo
  __shared__ float  sp1_l[20 * 18 * 16]; // pool1 spikes, padded, zero halo
  __shared__ int8_t s2_l[50 * 196];      // conv2 spikes (bytes)
  __shared__ float  m2_l[50 * 196];      // conv2 membranes
  __shared__ float  m2s_l[2450];         // pool2 membranes

  const int b  = blockIdx.x;
  const int t  = threadIdx.x;
  // P1 mapping
  const int lq = t & 255;
  const int ohu = __builtin_amdgcn_readfirstlane(t >> 8);
  const bool act1 = lq < 196;
  const int qy = lq / 14, qx = lq % 14;
  // P2 mapping: thread = (oc, row-pair)
  const bool act2 = t < 350;
  const int oc2 = t / 7;              // 0..49
  const int rp  = t % 7;              // 0..6
  const int y0  = 2 * rp;

  for (int p = t; p < 784; p += 512) {
    xhs_l[p] = x[b * 784 + p] * 0.5f;
  }
  // zero padded buffers (halos stay zero forever; data cells rewritten
  // every step before being read)
  for (int i = t; i < 1024; i += 512) pois_l[i] = 0.f;
  for (int i = t; i < 20 * 288; i += 512) sp1_l[i] = 0.f;
  for (int i = t; i < 50 * 196; i += 512) m2_l[i] = 0.f;
  for (int i = t; i < 2450; i += 512) m2s_l[i] = 0.f;

  // persistent register membranes: conv1 + pool1 only
  float m1r[4][10], m1sr[10];
#pragma unroll
  for (int i = 0; i < 10; ++i) {
    m1sr[i] = 0.f;
#pragma unroll
    for (int tt = 0; tt < 4; ++tt) m1r[tt][i] = 0.f;
  }
  __syncthreads();

  // poisson for step 0
  {
    uint32_t k0 = kb[0], k1 = kb[1];
    for (int p = t; p < 784; p += 512) {
      uint32_t o0, o1;
      tf2x32(k0, k1, 0u, (uint32_t)(b * 784 + p), o0, o1);
      float r = __uint_as_float(((o0 ^ o1) >> 9) | 0x3F800000u) - 1.0f;
      float v = xhs_l[p];
      pois_l[(p / 28 + 2) * 32 + (p % 28 + 2)] =
          (fabsf(v) > r) ? ((v > 0.f) ? 1.f : -1.f) : 0.f;
    }
  }
  __syncthreads();

  for (int s = 0; s < STEPS; ++s) {
    // ---- P1: conv1 (10 oc of this half) + fire + pool1 + fire ----
    if (act1) {
      // 6x6 padded input patch: rows 2qy..2qy+5, cols 2qx..2qx+5
      float u6[6][6];
#pragma unroll
      for (int rr = 0; rr < 6; ++rr) {
        const float2* pr = reinterpret_cast<const float2*>(
            &pois_l[(2 * qy + rr) * 32 + 2 * qx]);
        float2 a0 = pr[0], a1 = pr[1], a2 = pr[2];
        u6[rr][0] = a0.x; u6[rr][1] = a0.y;
        u6[rr][2] = a1.x; u6[rr][3] = a1.y;
        u6[rr][4] = a2.x; u6[rr][5] = a2.y;
      }
      float acc[4][10];
#pragma unroll
      for (int tt = 0; tt < 4; ++tt)
#pragma unroll
        for (int i = 0; i < 10; ++i) acc[tt][i] = 0.f;
#pragma unroll
      for (int ky = 0; ky < 5; ++ky) {
#pragma unroll
        for (int kx = 0; kx < 5; ++kx) {
#pragma unroll
          for (int i = 0; i < 10; ++i) {
            float w = w1[(ohu * 10 + i) * 25 + ky * 5 + kx];
#pragma unroll
            for (int tt = 0; tt < 4; ++tt)
              acc[tt][i] += w * u6[(tt >> 1) + ky][(tt & 1) + kx];
          }
        }
      }
#pragma unroll
      for (int i = 0; i < 10; ++i) {
        float s4[4];
#pragma unroll
        for (int tt = 0; tt < 4; ++tt) {
          float m = m1r[tt][i] + acc[tt][i];
          float sp = 0.f;
          if (m > 1.0f) { sp = 1.f; m = 0.f; }
          m1r[tt][i] = m;
          s4[tt] = sp;
        }
        float a = 0.25f * (((s4[0] + s4[1]) + s4[2]) + s4[3]);
        float mm = m1sr[i] + a;
        float spp = 0.f;
        if (mm > 0.75f) { spp = 1.f; mm = 0.f; }
        m1sr[i] = mm;
        sp1_l[(ohu * 10 + i) * 288 + (qy + 2) * 16 + (qx + 2)] = spp;
      }
    }
    __syncthreads();

    // ---- P2: conv2, padded vec4 u-rows shared across the row-pair ----
    if (act2) {
      float acc[2][14];
#pragma unroll
      for (int r = 0; r < 2; ++r)
#pragma unroll
        for (int xx = 0; xx < 14; ++xx) acc[r][xx] = 0.f;
#pragma unroll 1
      for (int ic = 0; ic < 20; ++ic) {
        float wv[25];
#pragma unroll
        for (int j = 0; j < 25; ++j)
          wv[j] = wT[(ic * 25 + j) * 50 + oc2];
        const float* spi = sp1_l + ic * 288;
#pragma unroll
        for (int jr = 0; jr < 6; ++jr) {
          const float4* rp4 =
              reinterpret_cast<const float4*>(spi + (y0 + jr) * 16);
          float4 rv0 = rp4[0], rv1 = rp4[1], rv2 = rp4[2], rv3 = rp4[3];
          float u[18];
          u[0]  = rv0.x; u[1]  = rv0.y; u[2]  = rv0.z; u[3]  = rv0.w;
          u[4]  = rv1.x; u[5]  = rv1.y; u[6]  = rv1.z; u[7]  = rv1.w;
          u[8]  = rv2.x; u[9]  = rv2.y; u[10] = rv2.z; u[11] = rv2.w;
          u[12] = rv3.x; u[13] = rv3.y; u[14] = rv3.z; u[15] = rv3.w;
          u[16] = 0.f;   u[17] = 0.f;   // padded cols 16,17 are always zero
          if (jr < 5) {                 // r=0, ky=jr
#pragma unroll
            for (int kx = 0; kx < 5; ++kx) {
              float w = wv[jr * 5 + kx];
#pragma unroll
              for (int xx = 0; xx < 14; ++xx)
                acc[0][xx] += w * u[xx + kx];
            }
          }
          if (jr >= 1) {                // r=1, ky=jr-1
#pragma unroll
            for (int kx = 0; kx < 5; ++kx) {
              float w = wv[(jr - 1) * 5 + kx];
#pragma unroll
              for (int xx = 0; xx < 14; ++xx)
                acc[1][xx] += w * u[xx + kx];
            }
          }
        }
      }
#pragma unroll
      for (int r = 0; r < 2; ++r) {
        int y = y0 + r;
#pragma unroll
        for (int xx = 0; xx < 14; ++xx) {
          int li = oc2 * 196 + y * 14 + xx;
          float m = m2_l[li] + acc[r][xx];
          int8_t sp = 0;
          if (m > 1.0f) { sp = 1; m = 0.f; }
          m2_l[li] = m;
          s2_l[li] = sp;
        }
      }
    }
    __syncthreads();

    // ---- P3: pool2 + fire -> ballot pack, + poisson(s+1) ----
#pragma unroll
    for (int i = 0; i < 5; ++i) {
      int e = i * 512 + t;
      bool fire = false;
      if (e < 2450) {
        int oc = e / 49, qq = e % 49;
        int yo = qq / 7, xo = qq % 7;
        int ib = oc * 196 + 2 * yo * 14 + 2 * xo;
        float s00 = (float)s2_l[ib];
        float s01 = (float)s2_l[ib + 1];
        float s10 = (float)s2_l[ib + 14];
        float s11 = (float)s2_l[ib + 15];
        float a = 0.25f * (((s00 + s01) + s10) + s11);
        float m = m2s_l[e] + a;
        if (m > 0.75f) { fire = true; m = 0.f; }
        m2s_l[e] = m;
      }
      unsigned long long mask = __ballot(fire);
      int base = (e & ~63);
      if ((t & 63) == 0 && base < 2450) {
        int d = base >> 5;
        sp2g[b * 7700 + s * 77 + d] = (uint32_t)mask;
        if (base + 32 < 2450)
          sp2g[b * 7700 + s * 77 + d + 1] = (uint32_t)(mask >> 32);
      }
    }
    if (s + 1 < STEPS) {
      uint32_t k0 = kb[2 * (s + 1)], k1 = kb[2 * (s + 1) + 1];
      for (int p = t; p < 784; p += 512) {
        uint32_t o0, o1;
        tf2x32(k0, k1, 0u, (uint32_t)(b * 784 + p), o0, o1);
        float r = __uint_as_float(((o0 ^ o1) >> 9) | 0x3F800000u) - 1.0f;
        float v = xhs_l[p];
        pois_l[(p / 28 + 2) * 32 + (p % 28 + 2)] =
            (fabsf(v) > r) ? ((v > 0.f) ? 1.f : -1.f) : 0.f;
      }
    }
    __syncthreads();
  }
}

// ---------------------------------------------------------------------------
// fc0 (R14-proven): block = sample, lane = neuron; wave-uniform ctz over
// spike bits; acc += wf0T[k][n] coalesced; k ascending -> bit-identical.
// ---------------------------------------------------------------------------
__global__ __launch_bounds__(256) void fc0f_k(
    const uint32_t* __restrict__ sp2g, const float* __restrict__ wf0T,
    float* __restrict__ Tf0g) {
  __shared__ uint32_t mk[77];
  const int b = blockIdx.x;
  const int n = threadIdx.x;
  float m = 0.f, T = 0.f;
  for (int s = 0; s < STEPS; ++s) {
    __syncthreads();
    if (n < 77) mk[n] = sp2g[b * 7700 + s * 77 + n];
    __syncthreads();
    float acc = 0.f;
    for (int d = 0; d < 77; ++d) {
      uint32_t um = mk[d];
      while (um) {
        int j = __builtin_ctz(um);
        um &= um - 1;
        acc += wf0T[((d << 5) + j) * 256 + n];
      }
    }
    m += acc;
    if (m > 1.0f) { T += 1.f; m = 0.f; }
  }
  if (n < 200) Tf0g[b * 200 + n] = T;
}

// ---------------------------------------------------------------------------
// final: out[b][i] = (Tf0[b][:] . wf1[i][:]) / 1 / 100   (j ascending)
// ---------------------------------------------------------------------------
__global__ void fc1_k(const float* __restrict__ Tf0,
                      const float* __restrict__ wf1,
                      float* __restrict__ out) {
  int idx = blockIdx.x * blockDim.x + threadIdx.x;
  if (idx >= 5120) return;
  int b = idx / 10, i = idx % 10;
  float a = 0.f;
  for (int j = 0; j < 200; ++j) a += Tf0[b * 200 + j] * wf1[i * 200 + j];
  out[idx] = (a / 1.0f) / 100.0f;
}

// ---------------------------------------------------------------------------
extern "C" void kernel_launch(void* const* d_in, const int* in_sizes, int n_in,
                              void* d_out, int out_size, void* d_ws, size_t ws_size,
                              hipStream_t stream) {
  (void)in_sizes; (void)n_in; (void)out_size; (void)ws_size;
  const float* x   = (const float*)d_in[0];
  const float* w1  = (const float*)d_in[1];
  const float* w2  = (const float*)d_in[2];
  const float* wf0 = (const float*)d_in[3];
  const float* wf1 = (const float*)d_in[4];
  float* out = (float*)d_out;
  char* ws = (char*)d_ws;

  // workspace: Tf0 | wT | keys | wf0T | sp2 bitmask  (~18.8 MB)
  const size_t tf0_b  = 512ull * 200 * 4;
  const size_t wt_b   = 25000ull * 4;
  const size_t key_b  = 1024;
  const size_t wf0t_b = 2450ull * 256 * 4;
  float*    Tf0g = (float*)ws;
  float*    wT   = (float*)(ws + tf0_b);
  uint32_t* kb   = (uint32_t*)(ws + tf0_b + wt_b);
  float*    wf0T = (float*)(ws + tf0_b + wt_b + key_b);
  uint32_t* sp2g = (uint32_t*)(ws + tf0_b + wt_b + key_b + wf0t_b);

  keys_k<<<1, 128, 0, stream>>>(kb);
  wt_k<<<98, 256, 0, stream>>>(w2, wT);
  wf0t_k<<<2450, 256, 0, stream>>>(wf0, wf0T);
  step_all_k<<<512, 512, 0, stream>>>(x, w1, wT, kb, sp2g);
  fc0f_k<<<512, 256, 0, stream>>>(sp2g, wf0T, Tf0g);
  fc1_k<<<20, 256, 0, stream>>>(Tf0g, wf1, out);
}

// Round 4
// 11318.163 us; speedup vs baseline: 1.3849x; 1.3849x over previous
//
#include <hip/hip_runtime.h>
#include <stdint.h>

#define STEPS 100

// ---------------------------------------------------------------------------
// Threefry2x32 (JAX-exact, 20 rounds)
// ---------------------------------------------------------------------------
__device__ __forceinline__ uint32_t rotl32(uint32_t v, int r) {
  return (v << r) | (v >> (32 - r));
}

__device__ __forceinline__ void tf2x32(uint32_t k0, uint32_t k1,
                                       uint32_t x0, uint32_t x1,
                                       uint32_t& o0, uint32_t& o1) {
  uint32_t ks2 = k0 ^ k1 ^ 0x1BD11BDAu;
  x0 += k0; x1 += k1;
#define RND(r) { x0 += x1; x1 = rotl32(x1, (r)); x1 ^= x0; }
  RND(13) RND(15) RND(26) RND(6)
  x0 += k1;  x1 += ks2 + 1u;
  RND(17) RND(29) RND(16) RND(24)
  x0 += ks2; x1 += k0 + 2u;
  RND(13) RND(15) RND(26) RND(6)
  x0 += k0;  x1 += k1 + 3u;
  RND(17) RND(29) RND(16) RND(24)
  x0 += k1;  x1 += ks2 + 4u;
  RND(13) RND(15) RND(26) RND(6)
  x0 += ks2; x1 += k0 + 5u;
#undef RND
  o0 = x0; o1 = x1;
}

__global__ void keys_k(uint32_t* __restrict__ kb) {
  int i = threadIdx.x;
  if (i < STEPS) {
    uint32_t a, b;
    tf2x32(0u, 42u, 0u, (uint32_t)i, a, b);
    kb[2 * i] = a;
    kb[2 * i + 1] = b;
  }
}

__global__ void wt_k(const float* __restrict__ w2, float* __restrict__ wT) {
  int i = blockIdx.x * blockDim.x + threadIdx.x;
  if (i >= 25000) return;
  int oc = i / 500, q = i % 500;
  wT[q * 50 + oc] = w2[i];
}

// wf0 transpose, padded: wf0T[k*256 + n] = (n<200) ? wf0[n*2450+k] : 0
__global__ void wf0t_k(const float* __restrict__ wf0,
                       float* __restrict__ wf0T) {
  int i = blockIdx.x * blockDim.x + threadIdx.x;
  if (i >= 2450 * 256) return;
  int k = i >> 8, n = i & 255;
  wf0T[i] = (n < 200) ? wf0[n * 2450 + k] : 0.f;
}

// ---------------------------------------------------------------------------
// PERSISTENT per-sample kernel v12: v11's guard-free vectorized loads, with
// the bank geometry FIXED (v11's stride-16 rows put all 7 rp-rows of a wave
// in one 4-bank group -> 5.5e9 conflict cycles = ~60% of wall):
//  * sp1 row stride 16 -> 20 floats (80 B, 16B-aligned): rp rows step 40
//    dwords -> bank +8 -> worst 2-way (free).
//  * pois row stride 32 -> 34 floats: qy rows step 68 dwords -> bank +4.
//  * Register diet to stay <=128 VGPR spill-free at launch_bounds(512,2):
//    P1 rolling 2-row window (rA/rB, same 6 row loads, same ky/kx order);
//    pool1 membranes m1sr -> LDS (m1s_l, +15.7 KB, 30 LDS ops/thr/step);
//    P2 drops always-zero u[16]/u[17] FMAs (adding exact +/-0 is bit-safe,
//    acc can never be -0 since it starts +0 and x+(-0)=x, (+0)+(-0)=+0).
// Per-output summation order (ic asc, ky asc, kx asc) preserved everywhere
// -> bit-identical output.
// LDS total: 3136+4624+28800+9800+39200+9800+15680 = 111040 B (1 blk/CU).
// ---------------------------------------------------------------------------
__global__ __launch_bounds__(512, 2) void step_all_k(
    const float* __restrict__ x, const float* __restrict__ w1,
    const float* __restrict__ wT, const uint32_t* __restrict__ kb,
    uint32_t* __restrict__ sp2g) {
  __shared__ __align__(16) float  xhs_l[784];          // x/2 (signed)
  __shared__ __align__(16) float  pois_l[32 * 34];     // padded, zero halo
  __shared__ __align__(16) float  sp1_l[20 * 18 * 20]; // padded, zero halo
  __shared__ int8_t s2_l[50 * 196];                    // conv2 spikes
  __shared__ __align__(16) float  m2_l[50 * 196];      // conv2 membranes
  __shared__ float  m2s_l[2450];                       // pool2 membranes
  __shared__ float  m1s_l[20 * 196];                   // pool1 membranes

  const int b  = blockIdx.x;
  const int t  = threadIdx.x;
  // P1 mapping
  const int lq = t & 255;
  const int ohu = __builtin_amdgcn_readfirstlane(t >> 8);
  const bool act1 = lq < 196;
  const int qy = lq / 14, qx = lq % 14;
  // P2 mapping: thread = (oc, row-pair)
  const bool act2 = t < 350;
  const int oc2 = t / 7;              // 0..49
  const int rp  = t % 7;              // 0..6
  const int y0  = 2 * rp;

  for (int p = t; p < 784; p += 512) {
    xhs_l[p] = x[b * 784 + p] * 0.5f;
  }
  // zero padded buffers (halos stay zero forever; data cells rewritten
  // every step before being read)
  for (int i = t; i < 32 * 34; i += 512) pois_l[i] = 0.f;
  for (int i = t; i < 20 * 360; i += 512) sp1_l[i] = 0.f;
  for (int i = t; i < 50 * 196; i += 512) m2_l[i] = 0.f;
  for (int i = t; i < 2450; i += 512) m2s_l[i] = 0.f;
  for (int i = t; i < 20 * 196; i += 512) m1s_l[i] = 0.f;

  // persistent register membranes: conv1 only
  float m1r[4][10];
#pragma unroll
  for (int i = 0; i < 10; ++i) {
#pragma unroll
    for (int tt = 0; tt < 4; ++tt) m1r[tt][i] = 0.f;
  }
  __syncthreads();

  // poisson for step 0
  {
    uint32_t k0 = kb[0], k1 = kb[1];
    for (int p = t; p < 784; p += 512) {
      uint32_t o0, o1;
      tf2x32(k0, k1, 0u, (uint32_t)(b * 784 + p), o0, o1);
      float r = __uint_as_float(((o0 ^ o1) >> 9) | 0x3F800000u) - 1.0f;
      float v = xhs_l[p];
      pois_l[(p / 28 + 2) * 34 + (p % 28 + 2)] =
          (fabsf(v) > r) ? ((v > 0.f) ? 1.f : -1.f) : 0.f;
    }
  }
  __syncthreads();

#define LDROW(rr, d) {                                                      \
    const float2* _pr = reinterpret_cast<const float2*>(                    \
        &pois_l[(2 * qy + (rr)) * 34 + 2 * qx]);                            \
    float2 _a0 = _pr[0], _a1 = _pr[1], _a2 = _pr[2];                        \
    d[0] = _a0.x; d[1] = _a0.y; d[2] = _a1.x;                               \
    d[3] = _a1.y; d[4] = _a2.x; d[5] = _a2.y; }

  for (int s = 0; s < STEPS; ++s) {
    // ---- P1: conv1 (10 oc of this half) + fire + pool1 + fire ----
    if (act1) {
      float rA[6], rB[6];
      LDROW(0, rA)
      LDROW(1, rB)
      float acc[4][10];
#pragma unroll
      for (int tt = 0; tt < 4; ++tt)
#pragma unroll
        for (int i = 0; i < 10; ++i) acc[tt][i] = 0.f;
#pragma unroll
      for (int ky = 0; ky < 5; ++ky) {
        // rA = padded row 2qy+ky (rows for tt 0,1), rB = row 2qy+ky+1
#pragma unroll
        for (int kx = 0; kx < 5; ++kx) {
#pragma unroll
          for (int i = 0; i < 10; ++i) {
            float w = w1[(ohu * 10 + i) * 25 + ky * 5 + kx];
            acc[0][i] += w * rA[kx];
            acc[1][i] += w * rA[kx + 1];
            acc[2][i] += w * rB[kx];
            acc[3][i] += w * rB[kx + 1];
          }
        }
        if (ky < 4) {
#pragma unroll
          for (int j = 0; j < 6; ++j) rA[j] = rB[j];
          LDROW(ky + 2, rB)
        }
      }
#pragma unroll
      for (int i = 0; i < 10; ++i) {
        float s4[4];
#pragma unroll
        for (int tt = 0; tt < 4; ++tt) {
          float m = m1r[tt][i] + acc[tt][i];
          float sp = 0.f;
          if (m > 1.0f) { sp = 1.f; m = 0.f; }
          m1r[tt][i] = m;
          s4[tt] = sp;
        }
        float a = 0.25f * (((s4[0] + s4[1]) + s4[2]) + s4[3]);
        int mi = (ohu * 10 + i) * 196 + lq;
        float mm = m1s_l[mi] + a;
        float spp = 0.f;
        if (mm > 0.75f) { spp = 1.f; mm = 0.f; }
        m1s_l[mi] = mm;
        sp1_l[(ohu * 10 + i) * 360 + (qy + 2) * 20 + (qx + 2)] = spp;
      }
    }
    __syncthreads();

    // ---- P2: conv2, padded vec4 u-rows shared across the row-pair ----
    if (act2) {
      float acc[2][14];
#pragma unroll
      for (int r = 0; r < 2; ++r)
#pragma unroll
        for (int xx = 0; xx < 14; ++xx) acc[r][xx] = 0.f;
#pragma unroll 1
      for (int ic = 0; ic < 20; ++ic) {
        float wv[25];
#pragma unroll
        for (int j = 0; j < 25; ++j)
          wv[j] = wT[(ic * 25 + j) * 50 + oc2];
        const float* spi = sp1_l + ic * 360;
#pragma unroll
        for (int jr = 0; jr < 6; ++jr) {
          const float4* rp4 =
              reinterpret_cast<const float4*>(spi + (y0 + jr) * 20);
          float4 rv0 = rp4[0], rv1 = rp4[1], rv2 = rp4[2], rv3 = rp4[3];
          float u[16];
          u[0]  = rv0.x; u[1]  = rv0.y; u[2]  = rv0.z; u[3]  = rv0.w;
          u[4]  = rv1.x; u[5]  = rv1.y; u[6]  = rv1.z; u[7]  = rv1.w;
          u[8]  = rv2.x; u[9]  = rv2.y; u[10] = rv2.z; u[11] = rv2.w;
          u[12] = rv3.x; u[13] = rv3.y; u[14] = rv3.z; u[15] = rv3.w;
          // cols 16,17 are padded zeros: their FMAs are dropped (bit-safe)
          if (jr < 5) {                 // r=0, ky=jr
#pragma unroll
            for (int kx = 0; kx < 5; ++kx) {
              float w = wv[jr * 5 + kx];
#pragma unroll
              for (int xx = 0; xx < 14; ++xx)
                if (xx + kx < 16) acc[0][xx] += w * u[xx + kx];
            }
          }
          if (jr >= 1) {                // r=1, ky=jr-1
#pragma unroll
            for (int kx = 0; kx < 5; ++kx) {
              float w = wv[(jr - 1) * 5 + kx];
#pragma unroll
              for (int xx = 0; xx < 14; ++xx)
                if (xx + kx < 16) acc[1][xx] += w * u[xx + kx];
            }
          }
        }
      }
#pragma unroll
      for (int r = 0; r < 2; ++r) {
        int y = y0 + r;
#pragma unroll
        for (int xx = 0; xx < 14; ++xx) {
          int li = oc2 * 196 + y * 14 + xx;
          float m = m2_l[li] + acc[r][xx];
          int8_t sp = 0;
          if (m > 1.0f) { sp = 1; m = 0.f; }
          m2_l[li] = m;
          s2_l[li] = sp;
        }
      }
    }
    __syncthreads();

    // ---- P3: pool2 + fire -> ballot pack, + poisson(s+1) ----
#pragma unroll
    for (int i = 0; i < 5; ++i) {
      int e = i * 512 + t;
      bool fire = false;
      if (e < 2450) {
        int oc = e / 49, qq = e % 49;
        int yo = qq / 7, xo = qq % 7;
        int ib = oc * 196 + 2 * yo * 14 + 2 * xo;
        float s00 = (float)s2_l[ib];
        float s01 = (float)s2_l[ib + 1];
        float s10 = (float)s2_l[ib + 14];
        float s11 = (float)s2_l[ib + 15];
        float a = 0.25f * (((s00 + s01) + s10) + s11);
        float m = m2s_l[e] + a;
        if (m > 0.75f) { fire = true; m = 0.f; }
        m2s_l[e] = m;
      }
      unsigned long long mask = __ballot(fire);
      int base = (e & ~63);
      if ((t & 63) == 0 && base < 2450) {
        int d = base >> 5;
        sp2g[b * 7700 + s * 77 + d] = (uint32_t)mask;
        if (base + 32 < 2450)
          sp2g[b * 7700 + s * 77 + d + 1] = (uint32_t)(mask >> 32);
      }
    }
    if (s + 1 < STEPS) {
      uint32_t k0 = kb[2 * (s + 1)], k1 = kb[2 * (s + 1) + 1];
      for (int p = t; p < 784; p += 512) {
        uint32_t o0, o1;
        tf2x32(k0, k1, 0u, (uint32_t)(b * 784 + p), o0, o1);
        float r = __uint_as_float(((o0 ^ o1) >> 9) | 0x3F800000u) - 1.0f;
        float v = xhs_l[p];
        pois_l[(p / 28 + 2) * 34 + (p % 28 + 2)] =
            (fabsf(v) > r) ? ((v > 0.f) ? 1.f : -1.f) : 0.f;
      }
    }
    __syncthreads();
  }
#undef LDROW
}

// ---------------------------------------------------------------------------
// fc0 (R14-proven): block = sample, lane = neuron; wave-uniform ctz over
// spike bits; acc += wf0T[k][n] coalesced; k ascending -> bit-identical.
// ---------------------------------------------------------------------------
__global__ __launch_bounds__(256) void fc0f_k(
    const uint32_t* __restrict__ sp2g, const float* __restrict__ wf0T,
    float* __restrict__ Tf0g) {
  __shared__ uint32_t mk[77];
  const int b = blockIdx.x;
  const int n = threadIdx.x;
  float m = 0.f, T = 0.f;
  for (int s = 0; s < STEPS; ++s) {
    __syncthreads();
    if (n < 77) mk[n] = sp2g[b * 7700 + s * 77 + n];
    __syncthreads();
    float acc = 0.f;
    for (int d = 0; d < 77; ++d) {
      uint32_t um = mk[d];
      while (um) {
        int j = __builtin_ctz(um);
        um &= um - 1;
        acc += wf0T[((d << 5) + j) * 256 + n];
      }
    }
    m += acc;
    if (m > 1.0f) { T += 1.f; m = 0.f; }
  }
  if (n < 200) Tf0g[b * 200 + n] = T;
}

// ---------------------------------------------------------------------------
// final: out[b][i] = (Tf0[b][:] . wf1[i][:]) / 1 / 100   (j ascending)
// ---------------------------------------------------------------------------
__global__ void fc1_k(const float* __restrict__ Tf0,
                      const float* __restrict__ wf1,
                      float* __restrict__ out) {
  int idx = blockIdx.x * blockDim.x + threadIdx.x;
  if (idx >= 5120) return;
  int b = idx / 10, i = idx % 10;
  float a = 0.f;
  for (int j = 0; j < 200; ++j) a += Tf0[b * 200 + j] * wf1[i * 200 + j];
  out[idx] = (a / 1.0f) / 100.0f;
}

// ---------------------------------------------------------------------------
extern "C" void kernel_launch(void* const* d_in, const int* in_sizes, int n_in,
                              void* d_out, int out_size, void* d_ws, size_t ws_size,
                              hipStream_t stream) {
  (void)in_sizes; (void)n_in; (void)out_size; (void)ws_size;
  const float* x   = (const float*)d_in[0];
  const float* w1  = (const float*)d_in[1];
  const float* w2  = (const float*)d_in[2];
  const float* wf0 = (const float*)d_in[3];
  const float* wf1 = (const float*)d_in[4];
  float* out = (float*)d_out;
  char* ws = (char*)d_ws;

  // workspace: Tf0 | wT | keys | wf0T | sp2 bitmask  (~18.8 MB)
  const size_t tf0_b  = 512ull * 200 * 4;
  const size_t wt_b   = 25000ull * 4;
  const size_t key_b  = 1024;
  const size_t wf0t_b = 2450ull * 256 * 4;
  float*    Tf0g = (float*)ws;
  float*    wT   = (float*)(ws + tf0_b);
  uint32_t* kb   = (uint32_t*)(ws + tf0_b + wt_b);
  float*    wf0T = (float*)(ws + tf0_b + wt_b + key_b);
  uint32_t* sp2g = (uint32_t*)(ws + tf0_b + wt_b + key_b + wf0t_b);

  keys_k<<<1, 128, 0, stream>>>(kb);
  wt_k<<<98, 256, 0, stream>>>(w2, wT);
  wf0t_k<<<2450, 256, 0, stream>>>(wf0, wf0T);
  step_all_k<<<512, 512, 0, stream>>>(x, w1, wT, kb, sp2g);
  fc0f_k<<<512, 256, 0, stream>>>(sp2g, wf0T, Tf0g);
  fc1_k<<<20, 256, 0, stream>>>(Tf0g, wf1, out);
}